// Round 9
// baseline (1259.556 us; speedup 1.0000x reference)
//
#include <hip/hip_runtime.h>

#define NXc 256
#define NTc 256
#define NBLK 128          // 2 batches x 64 blocks, 4 own rows each
#define NGRP 128          // 2 timesteps per group
#define DTv 0.0005f
#define INVD 0.2f

// ws float-offsets
#define COEF_OFF 0        // 1024 floats
#define TAGS_OFF 1024     // 256 u32 (one per block x wave)
#define EX_OFF   2048     // [2 parity][128 blk][52 entry][256 col] f32
#define EX_BLK   13312    // 52*256
// entries: 0-11 ST[f][r] (syy,sxy,sxx x rows 0..3) ; 12-19 VL[f][r] (vy,vx)
//          20-35 MYV[v][r] (myy,mxyy,myx,mxx) ; 36-51 MVV[v][r] (mvyy,mvxy,mvyx,mvxx)

__device__ __forceinline__ float ald(const float* p) {
  return __hip_atomic_load(p, __ATOMIC_RELAXED, __HIP_MEMORY_SCOPE_AGENT);
}
__device__ __forceinline__ void ast(float* p, float v) {
  __hip_atomic_store(p, v, __ATOMIC_RELAXED, __HIP_MEMORY_SCOPE_AGENT);
}
__device__ __forceinline__ unsigned uld(const unsigned* p) {
  return __hip_atomic_load(p, __ATOMIC_RELAXED, __HIP_MEMORY_SCOPE_AGENT);
}
__device__ __forceinline__ void ust(unsigned* p, unsigned v) {
  __hip_atomic_store(p, v, __ATOMIC_RELAXED, __HIP_MEMORY_SCOPE_AGENT);
}
__device__ __forceinline__ void bar_lds() {
  asm volatile("s_waitcnt lgkmcnt(0)" ::: "memory");
  __builtin_amdgcn_s_barrier();
  asm volatile("" ::: "memory");
}
__device__ __forceinline__ bool pml(int i) { return (i < 20) || (i >= 236); }

__device__ __forceinline__ void rec_write(float* out, unsigned long long m0,
                                          unsigned long long m1, int t, float v) {
  while (m0) { int i = __ffsll((long long)m0)-1; m0 &= m0-1; out[i*NTc + t] = v; }
  while (m1) { int i = __ffsll((long long)m1)-1; m1 &= m1-1; out[(i+64)*NTc + t] = v; }
}

__global__ __launch_bounds__(256) void setup_kernel(
    const float* __restrict__ lamb, const float* __restrict__ mu,
    const float* __restrict__ buoy, float* __restrict__ coef)
{
  __shared__ float red[256];
  const int tid = threadIdx.x;
  float m = 0.0f;
  for (int i = tid; i < 256*256; i += 256)
    m = fmaxf(m, sqrtf((lamb[i] + 2.0f*mu[i]) * buoy[i]));
  red[tid] = m;
  __syncthreads();
  for (int s = 128; s > 0; s >>= 1) {
    if (tid < s) red[tid] = fmaxf(red[tid], red[tid+s]);
    __syncthreads();
  }
  const float maxv = red[0];
  const float i_f = (float)tid;
  const float w = 20.0f;
  float f1 = fminf(fmaxf((w - i_f) * (1.0f/w), 0.0f), 1.0f);
  float f2 = fminf(fmaxf((i_f - (256.0f - 1.0f - w)) * (1.0f/w), 0.0f), 1.0f);
  float frac = fmaxf(f1, f2);
  float sigma_max = 3.0f * maxv * 6.907755278982137f / (2.0f * w * 5.0f);
  float sigma = sigma_max * frac * frac;
  float alpha = 3.14159265358979323f * 25.0f * (1.0f - frac);
  float bc = expf(-(sigma + alpha) * 0.0005f);
  float ac = sigma / (sigma + alpha + 1e-9f) * (bc - 1.0f);
  coef[tid]       = ac;  // ay
  coef[256 + tid] = bc;  // by
  coef[512 + tid] = ac;  // ax
  coef[768 + tid] = bc;  // bx
}

__global__ __launch_bounds__(512) void elastic_k2(
    const float* __restrict__ lamb_g, const float* __restrict__ mu_g,
    const float* __restrict__ buoy_g, const float* __restrict__ amps,
    const int* __restrict__ src_loc, const int* __restrict__ rec_loc,
    float* __restrict__ ws, float* __restrict__ out)
{
  __shared__ float Vb[2][10][NXc];   // velocity rows lo-3 .. lo+6
  __shared__ float Sb[3][12][NXc];   // stress rows lo-4 .. lo+7

  const int blk = blockIdx.x;
  const int b = blk >> 6, bi = blk & 63;
  const int tid = threadIdx.x;
  const int ty = tid >> 8, tx = tid & 255;   // ty wave-uniform
  const int lo = bi << 2;
  const bool hasUp = bi > 0, hasDn = bi < 63;

  const float* coef = ws + COEF_OFF;
  unsigned* tags = (unsigned*)(ws + TAGS_OFF);
  float* exbase = ws + EX_OFF;

  const int txm = tx ? tx-1 : 0;
  const int txp = (tx < 255) ? tx+1 : 255;
  const bool xm_ok = tx > 0, xp_ok = tx < 255;
  const bool xpml = (tx < 20) || (tx >= 236);
  const float axv = coef[512+tx], bxv = coef[768+tx];

  // velocity cells k=0..4, row lo-3+ty+2k  (own: ty0 -> k2,k3 ; ty1 -> k1,k2)
  float vyv[5], vxv[5], myy[5], myx[5], mxyy[5], mxx[5];
  float vdtb[5], vay[5], vby[5];
  #pragma unroll
  for (int k = 0; k < 5; ++k) {
    const int gy = lo - 3 + ty + 2*k;
    const bool ok = (gy >= 0) && (gy < 256);
    const int gc = ok ? gy : 0;
    vdtb[k] = ok ? DTv * buoy_g[gc*NXc + tx] : 0.f;
    vay[k]  = ok ? coef[gc] : 0.f;
    vby[k]  = ok ? coef[256+gc] : 1.f;
    vyv[k]=vxv[k]=myy[k]=myx[k]=mxyy[k]=mxx[k]=0.f;
  }
  // stress cells j=0..3, row lo-2+ty+2j  (own: j1,j2 both ty)
  float syv[4], sxyv[4], sxxv[4], mvyy[4], mvxx[4], mvyx[4], mvxy[4];
  float slam[4], smu[4], sl2m[4], say[4], sby[4];
  #pragma unroll
  for (int j = 0; j < 4; ++j) {
    const int gy = lo - 2 + ty + 2*j;
    const bool ok = (gy >= 0) && (gy < 256);
    const int gc = ok ? gy : 0;
    slam[j] = ok ? lamb_g[gc*NXc+tx] : 0.f;
    smu[j]  = ok ? mu_g[gc*NXc+tx] : 0.f;
    sl2m[j] = slam[j] + 2.f*smu[j];
    say[j]  = ok ? coef[gc] : 0.f;
    sby[j]  = ok ? coef[256+gc] : 1.f;
    syv[j]=sxyv[j]=sxxv[j]=mvyy[j]=mvxx[j]=mvyx[j]=mvxy[j]=0.f;
  }

  // sources (any of the 5 v-cells; halo replicas inject consistently)
  int sk0=-1, sk1=-1, so0=0, so1=0;
  for (int i = 0; i < 4; ++i) {
    const int sb = i >> 1, sy = src_loc[2*i], sx = src_loc[2*i+1];
    if (sb == b && sx == tx) {
      #pragma unroll
      for (int k = 0; k < 5; ++k) {
        const int gy = lo - 3 + ty + 2*k;
        if (gy == sy) { if (sk0 < 0) { sk0=k; so0=i*NTc; } else { sk1=k; so1=i*NTc; } }
      }
    }
  }
  // receivers: own cells only (each row has exactly one owner thread)
  const int gyA = ty ? lo : lo + 1;       // own cell A: ty0 k2 / ty1 k1
  const int gyB = ty ? lo + 2 : lo + 3;   // own cell B: ty0 k3 / ty1 k2
  unsigned long long mA0=0,mA1=0,mB0=0,mB1=0;
  for (int i = 0; i < 128; ++i) {
    const int rb = i >> 6, ry = rec_loc[2*i], rx = rec_loc[2*i+1];
    if (rb == b && rx == tx) {
      if (ry == gyA) { if (i<64) mA0 |= 1ull<<i; else mA1 |= 1ull<<(i-64); }
      if (ry == gyB) { if (i<64) mB0 |= 1ull<<i; else mB1 |= 1ull<<(i-64); }
    }
  }
  const bool recA = (mA0|mA1)!=0ull, recB = (mB0|mB1)!=0ull;

  // zero LDS
  { float* p = &Vb[0][0][0]; for (int i = tid; i < 2*10*NXc; i += 512) p[i]=0.f;
    float* q = &Sb[0][0][0]; for (int i = tid; i < 3*12*NXc; i += 512) q[i]=0.f; }
  __syncthreads();

  for (int g = 0; g < NGRP; ++g) {
    const int t0 = 2*g, t1 = 2*g+1;
    float a00=0.f,a01=0.f,a10=0.f,a11=0.f;
    if (sk0>=0) { a00=amps[so0+t0]; a01=amps[so0+t1]; }
    if (sk1>=0) { a10=amps[so1+t0]; a11=amps[so1+t1]; }

    // ================= X: poll + ingest (state t0-1) =================
    if (g > 0) {
      const unsigned want = (unsigned)g;
      if (hasUp) { const unsigned* f = &tags[(blk-1)*2+ty]; while (uld(f) < want) {} }
      if (hasDn) { const unsigned* f = &tags[(blk+1)*2+ty]; while (uld(f) < want) {} }
      asm volatile("" ::: "memory");
      const int par = (g-1)&1;
      if (hasUp) {
        const float* P = exbase + (size_t)(par*NBLK + blk-1)*EX_BLK + tx;
        // stress rows lo-4+ty (Sidx ty, r=ty) and lo-2+ty (Sidx ty+2, r=ty+2)
        const float s0a=ald(P+(0*4+ty)*NXc),   s1a=ald(P+(1*4+ty)*NXc),   s2a=ald(P+(2*4+ty)*NXc);
        const float s0b=ald(P+(0*4+ty+2)*NXc), s1b=ald(P+(1*4+ty+2)*NXc), s2b=ald(P+(2*4+ty+2)*NXc);
        Sb[0][ty][tx]=s0a;   Sb[1][ty][tx]=s1a;   Sb[2][ty][tx]=s2a;
        Sb[0][ty+2][tx]=s0b; Sb[1][ty+2][tx]=s1b; Sb[2][ty+2][tx]=s2b;
        syv[0]=s0b; sxyv[0]=s1b; sxxv[0]=s2b;            // j=0 row lo-2+ty
        if (pml(lo-2+ty)) { mvyy[0]=ald(P+(36+ty+2)*NXc); mvxy[0]=ald(P+(40+ty+2)*NXc); }
        else { mvyy[0]=0.f; mvxy[0]=0.f; }
        if (xpml) { mvyx[0]=ald(P+(44+ty+2)*NXc); mvxx[0]=ald(P+(48+ty+2)*NXc); }
        else { mvyx[0]=0.f; mvxx[0]=0.f; }
        if (ty == 0) {     // k0 row lo-3 (r=1); k1 row lo-1 (r=3)
          vyv[0]=ald(P+13*NXc); vxv[0]=ald(P+17*NXc);
          vyv[1]=ald(P+15*NXc); vxv[1]=ald(P+19*NXc);
          if (pml(lo-3)) { myy[0]=ald(P+21*NXc); mxyy[0]=ald(P+25*NXc); } else { myy[0]=0.f; mxyy[0]=0.f; }
          if (pml(lo-1)) { myy[1]=ald(P+23*NXc); mxyy[1]=ald(P+27*NXc); } else { myy[1]=0.f; mxyy[1]=0.f; }
          if (xpml) { myx[0]=ald(P+29*NXc); mxx[0]=ald(P+33*NXc);
                      myx[1]=ald(P+31*NXc); mxx[1]=ald(P+35*NXc); }
          else { myx[0]=mxx[0]=myx[1]=mxx[1]=0.f; }
        } else {           // k0 row lo-2 (r=2)
          vyv[0]=ald(P+14*NXc); vxv[0]=ald(P+18*NXc);
          if (pml(lo-2)) { myy[0]=ald(P+22*NXc); mxyy[0]=ald(P+26*NXc); } else { myy[0]=0.f; mxyy[0]=0.f; }
          if (xpml) { myx[0]=ald(P+30*NXc); mxx[0]=ald(P+34*NXc); } else { myx[0]=mxx[0]=0.f; }
        }
      }
      if (hasDn) {
        const float* P = exbase + (size_t)(par*NBLK + blk+1)*EX_BLK + tx;
        // stress rows lo+4+ty (Sidx 8+ty, r=ty) and lo+6+ty (Sidx 10+ty, r=ty+2)
        const float s0a=ald(P+(0*4+ty)*NXc),   s1a=ald(P+(1*4+ty)*NXc),   s2a=ald(P+(2*4+ty)*NXc);
        const float s0b=ald(P+(0*4+ty+2)*NXc), s1b=ald(P+(1*4+ty+2)*NXc), s2b=ald(P+(2*4+ty+2)*NXc);
        Sb[0][8+ty][tx]=s0a;  Sb[1][8+ty][tx]=s1a;  Sb[2][8+ty][tx]=s2a;
        Sb[0][10+ty][tx]=s0b; Sb[1][10+ty][tx]=s1b; Sb[2][10+ty][tx]=s2b;
        syv[3]=s0a; sxyv[3]=s1a; sxxv[3]=s2a;            // j=3 row lo+4+ty
        if (pml(lo+4+ty)) { mvyy[3]=ald(P+(36+ty)*NXc); mvxy[3]=ald(P+(40+ty)*NXc); }
        else { mvyy[3]=0.f; mvxy[3]=0.f; }
        if (xpml) { mvyx[3]=ald(P+(44+ty)*NXc); mvxx[3]=ald(P+(48+ty)*NXc); }
        else { mvyx[3]=0.f; mvxx[3]=0.f; }
        if (ty == 0) {     // k4 row lo+5 (r=1)
          vyv[4]=ald(P+13*NXc); vxv[4]=ald(P+17*NXc);
          if (pml(lo+5)) { myy[4]=ald(P+21*NXc); mxyy[4]=ald(P+25*NXc); } else { myy[4]=0.f; mxyy[4]=0.f; }
          if (xpml) { myx[4]=ald(P+29*NXc); mxx[4]=ald(P+33*NXc); } else { myx[4]=mxx[4]=0.f; }
        } else {           // k3 row lo+4 (r=0); k4 row lo+6 (r=2)
          vyv[3]=ald(P+12*NXc); vxv[3]=ald(P+16*NXc);
          vyv[4]=ald(P+14*NXc); vxv[4]=ald(P+18*NXc);
          if (pml(lo+4)) { myy[3]=ald(P+20*NXc); mxyy[3]=ald(P+24*NXc); } else { myy[3]=0.f; mxyy[3]=0.f; }
          if (pml(lo+6)) { myy[4]=ald(P+22*NXc); mxyy[4]=ald(P+26*NXc); } else { myy[4]=0.f; mxyy[4]=0.f; }
          if (xpml) { myx[3]=ald(P+28*NXc); mxx[3]=ald(P+32*NXc);
                      myx[4]=ald(P+30*NXc); mxx[4]=ald(P+34*NXc); }
          else { myx[3]=mxx[3]=myx[4]=mxx[4]=0.f; }
        }
      }
    }
    bar_lds();                                   // barrier 1

    // ================= A0: velocity(t0), k=0..4 =================
    #pragma unroll
    for (int k = 0; k < 5; ++k) {
      const int gy = lo - 3 + ty + 2*k;
      if (gy >= 0 && gy < 256) {
        const int si = ty + 2*k + 1;
        float d,u1,u2,u3,u4;
        d = (gy > 0) ? (Sb[0][si][tx]-Sb[0][si-1][tx])*INVD : 0.f;
        myy[k] = vby[k]*myy[k] + vay[k]*d; u1 = d+myy[k];
        d = xm_ok ? (Sb[1][si][tx]-Sb[1][si][txm])*INVD : 0.f;
        myx[k] = bxv*myx[k] + axv*d; u2 = d+myx[k];
        vyv[k] += vdtb[k]*(u1+u2);
        d = (gy < 255) ? (Sb[1][si+1][tx]-Sb[1][si][tx])*INVD : 0.f;
        mxyy[k] = vby[k]*mxyy[k] + vay[k]*d; u3 = d+mxyy[k];
        d = xp_ok ? (Sb[2][si][txp]-Sb[2][si][tx])*INVD : 0.f;
        mxx[k] = bxv*mxx[k] + axv*d; u4 = d+mxx[k];
        vxv[k] += vdtb[k]*(u3+u4);
        if (k==sk0) vyv[k] += a00*vdtb[k];
        if (k==sk1) vyv[k] += a10*vdtb[k];
        Vb[0][ty+2*k][tx] = vyv[k];
        Vb[1][ty+2*k][tx] = vxv[k];
      }
    }
    if (recA) rec_write(out, mA0, mA1, t0, ty ? vyv[1] : vyv[2]);
    if (recB) rec_write(out, mB0, mB1, t0, ty ? vyv[2] : vyv[3]);
    bar_lds();                                   // barrier 2

    // ================= B0: stress(t0), j=0..3 =================
    #pragma unroll
    for (int j = 0; j < 4; ++j) {
      const int gy = lo - 2 + ty + 2*j;
      if (gy >= 0 && gy < 256) {
        const int vr = ty + 2*j + 1;
        float d,u5,u6,u7,u8;
        d = (gy < 255) ? (Vb[0][vr+1][tx]-Vb[0][vr][tx])*INVD : 0.f;
        mvyy[j] = sby[j]*mvyy[j] + say[j]*d; u5 = d+mvyy[j];
        d = xm_ok ? (Vb[1][vr][tx]-Vb[1][vr][txm])*INVD : 0.f;
        mvxx[j] = bxv*mvxx[j] + axv*d; u6 = d+mvxx[j];
        syv[j]  += DTv*(sl2m[j]*u5 + slam[j]*u6);
        sxxv[j] += DTv*(slam[j]*u5 + sl2m[j]*u6);
        d = xm_ok ? (Vb[0][vr][tx]-Vb[0][vr][txm])*INVD : 0.f;
        mvyx[j] = bxv*mvyx[j] + axv*d; u7 = d+mvyx[j];
        d = (gy > 0) ? (Vb[1][vr][tx]-Vb[1][vr-1][tx])*INVD : 0.f;
        mvxy[j] = sby[j]*mvxy[j] + say[j]*d; u8 = d+mvxy[j];
        sxyv[j] += DTv*smu[j]*(u7+u8);
        Sb[0][ty+2*j+2][tx]=syv[j];
        Sb[1][ty+2*j+2][tx]=sxyv[j];
        Sb[2][ty+2*j+2][tx]=sxxv[j];
      }
    }
    bar_lds();                                   // barrier 3

    // ================= A1: velocity(t1), k=1..3 =================
    #pragma unroll
    for (int k = 1; k < 4; ++k) {
      const int gy = lo - 3 + ty + 2*k;
      if (gy >= 0 && gy < 256) {
        const int si = ty + 2*k + 1;
        float d,u1,u2,u3,u4;
        d = (gy > 0) ? (Sb[0][si][tx]-Sb[0][si-1][tx])*INVD : 0.f;
        myy[k] = vby[k]*myy[k] + vay[k]*d; u1 = d+myy[k];
        d = xm_ok ? (Sb[1][si][tx]-Sb[1][si][txm])*INVD : 0.f;
        myx[k] = bxv*myx[k] + axv*d; u2 = d+myx[k];
        vyv[k] += vdtb[k]*(u1+u2);
        d = (gy < 255) ? (Sb[1][si+1][tx]-Sb[1][si][tx])*INVD : 0.f;
        mxyy[k] = vby[k]*mxyy[k] + vay[k]*d; u3 = d+mxyy[k];
        d = xp_ok ? (Sb[2][si][txp]-Sb[2][si][tx])*INVD : 0.f;
        mxx[k] = bxv*mxx[k] + axv*d; u4 = d+mxx[k];
        vxv[k] += vdtb[k]*(u3+u4);
        if (k==sk0) vyv[k] += a01*vdtb[k];
        if (k==sk1) vyv[k] += a11*vdtb[k];
        Vb[0][ty+2*k][tx] = vyv[k];
        Vb[1][ty+2*k][tx] = vxv[k];
      }
    }
    if (recA) rec_write(out, mA0, mA1, t1, ty ? vyv[1] : vyv[2]);
    if (recB) rec_write(out, mB0, mB1, t1, ty ? vyv[2] : vyv[3]);

    // egress v-part (overlaps barrier4 + B1)
    float* Q = exbase + (size_t)((g&1)*NBLK + blk)*EX_BLK + tx;
    if (g < NGRP-1) {
      if (ty == 0) {   // k2 row lo+1 (r=1); k3 row lo+3 (r=3)
        ast(Q+13*NXc, vyv[2]); ast(Q+17*NXc, vxv[2]);
        ast(Q+15*NXc, vyv[3]); ast(Q+19*NXc, vxv[3]);
        if (pml(lo+1)) { ast(Q+21*NXc, myy[2]); ast(Q+25*NXc, mxyy[2]); }
        if (pml(lo+3)) { ast(Q+23*NXc, myy[3]); ast(Q+27*NXc, mxyy[3]); }
        if (xpml) { ast(Q+29*NXc, myx[2]); ast(Q+33*NXc, mxx[2]);
                    ast(Q+31*NXc, myx[3]); ast(Q+35*NXc, mxx[3]); }
      } else {         // k1 row lo (r=0); k2 row lo+2 (r=2)
        ast(Q+12*NXc, vyv[1]); ast(Q+16*NXc, vxv[1]);
        ast(Q+14*NXc, vyv[2]); ast(Q+18*NXc, vxv[2]);
        if (pml(lo))   { ast(Q+20*NXc, myy[1]); ast(Q+24*NXc, mxyy[1]); }
        if (pml(lo+2)) { ast(Q+22*NXc, myy[2]); ast(Q+26*NXc, mxyy[2]); }
        if (xpml) { ast(Q+28*NXc, myx[1]); ast(Q+32*NXc, mxx[1]);
                    ast(Q+30*NXc, myx[2]); ast(Q+34*NXc, mxx[2]); }
      }
    }
    bar_lds();                                   // barrier 4

    // ================= B1: stress(t1), own j=1,2 =================
    #pragma unroll
    for (int j = 1; j < 3; ++j) {
      const int gy = lo - 2 + ty + 2*j;          // always in [0,255]
      const int vr = ty + 2*j + 1;
      float d,u5,u6,u7,u8;
      d = (gy < 255) ? (Vb[0][vr+1][tx]-Vb[0][vr][tx])*INVD : 0.f;
      mvyy[j] = sby[j]*mvyy[j] + say[j]*d; u5 = d+mvyy[j];
      d = xm_ok ? (Vb[1][vr][tx]-Vb[1][vr][txm])*INVD : 0.f;
      mvxx[j] = bxv*mvxx[j] + axv*d; u6 = d+mvxx[j];
      syv[j]  += DTv*(sl2m[j]*u5 + slam[j]*u6);
      sxxv[j] += DTv*(slam[j]*u5 + sl2m[j]*u6);
      d = xm_ok ? (Vb[0][vr][tx]-Vb[0][vr][txm])*INVD : 0.f;
      mvyx[j] = bxv*mvyx[j] + axv*d; u7 = d+mvyx[j];
      d = (gy > 0) ? (Vb[1][vr][tx]-Vb[1][vr-1][tx])*INVD : 0.f;
      mvxy[j] = sby[j]*mvxy[j] + say[j]*d; u8 = d+mvxy[j];
      sxyv[j] += DTv*smu[j]*(u7+u8);
      Sb[0][ty+2*j+2][tx]=syv[j];
      Sb[1][ty+2*j+2][tx]=sxyv[j];
      Sb[2][ty+2*j+2][tx]=sxxv[j];
    }

    // egress s-part + drain + tag
    if (g < NGRP-1) {
      if (ty == 0) {   // j1 row lo (r=0); j2 row lo+2 (r=2)
        ast(Q+0*NXc, syv[1]); ast(Q+4*NXc, sxyv[1]); ast(Q+8*NXc, sxxv[1]);
        ast(Q+2*NXc, syv[2]); ast(Q+6*NXc, sxyv[2]); ast(Q+10*NXc, sxxv[2]);
        if (pml(lo))   { ast(Q+36*NXc, mvyy[1]); ast(Q+40*NXc, mvxy[1]); }
        if (pml(lo+2)) { ast(Q+38*NXc, mvyy[2]); ast(Q+42*NXc, mvxy[2]); }
        if (xpml) { ast(Q+44*NXc, mvyx[1]); ast(Q+48*NXc, mvxx[1]);
                    ast(Q+46*NXc, mvyx[2]); ast(Q+50*NXc, mvxx[2]); }
      } else {         // j1 row lo+1 (r=1); j2 row lo+3 (r=3)
        ast(Q+1*NXc, syv[1]); ast(Q+5*NXc, sxyv[1]); ast(Q+9*NXc, sxxv[1]);
        ast(Q+3*NXc, syv[2]); ast(Q+7*NXc, sxyv[2]); ast(Q+11*NXc, sxxv[2]);
        if (pml(lo+1)) { ast(Q+37*NXc, mvyy[1]); ast(Q+41*NXc, mvxy[1]); }
        if (pml(lo+3)) { ast(Q+39*NXc, mvyy[2]); ast(Q+43*NXc, mvxy[2]); }
        if (xpml) { ast(Q+45*NXc, mvyx[1]); ast(Q+49*NXc, mvxx[1]);
                    ast(Q+47*NXc, mvyx[2]); ast(Q+51*NXc, mvxx[2]); }
      }
      asm volatile("s_waitcnt vmcnt(0)" ::: "memory");   // wave-wide drain
      if (tx == 0) ust(&tags[blk*2+ty], (unsigned)(g+1));
    }
  }
}

extern "C" void kernel_launch(void* const* d_in, const int* in_sizes, int n_in,
                              void* d_out, int out_size, void* d_ws, size_t ws_size,
                              hipStream_t stream) {
  const float* lamb    = (const float*)d_in[0];
  const float* mu      = (const float*)d_in[1];
  const float* buoy    = (const float*)d_in[2];
  const float* amps    = (const float*)d_in[3];
  const int*   src_loc = (const int*)d_in[4];
  const int*   rec_loc = (const int*)d_in[5];
  float* out = (float*)d_out;
  float* ws  = (float*)d_ws;

  // tags must start at 0 every launch (monotonic 1..127 within a run)
  hipMemsetAsync((char*)ws + TAGS_OFF*sizeof(float), 0, 256*sizeof(unsigned), stream);

  hipLaunchKernelGGL(setup_kernel, dim3(1), dim3(256), 0, stream,
                     lamb, mu, buoy, ws + COEF_OFF);

  void* args[] = { (void*)&lamb, (void*)&mu, (void*)&buoy, (void*)&amps,
                   (void*)&src_loc, (void*)&rec_loc, (void*)&ws, (void*)&out };
  hipLaunchCooperativeKernel((void*)elastic_k2, dim3(NBLK), dim3(512),
                             args, 0, stream);
}

// Round 10
// 787.034 us; speedup vs baseline: 1.6004x; 1.6004x over previous
//
#include <hip/hip_runtime.h>

#define NXc 256
#define NTc 256
#define NBLK 128          // 2 batches x 64 blocks x 4 rows
#define DTv 0.0005f
#define INVD 0.2f

// ws float offsets
#define COEF_OFF 0        // 1024 floats
#define EX_OFF  1024      // byte off 4096, 8B aligned: u64[2 par][128 blk][8 entry][256 col]
#define EX_BLK  2048      // u64 per block slot
// producer entries (rows are producer's own): 0=syy[lo] 1=sxy[lo] 2=sxy[lo+1] 3=sxx[lo]
//                                             4=syy[lo+2] 5=syy[lo+3] 6=sxy[lo+3] 7=sxx[lo+3]

__device__ __forceinline__ unsigned long long tld(const unsigned long long* p) {
  return __hip_atomic_load(p, __ATOMIC_RELAXED, __HIP_MEMORY_SCOPE_AGENT);
}
__device__ __forceinline__ void tst(unsigned long long* p, float v, unsigned tag) {
  unsigned long long u = ((unsigned long long)tag << 32) | (unsigned long long)__float_as_uint(v);
  __hip_atomic_store(p, u, __ATOMIC_RELAXED, __HIP_MEMORY_SCOPE_AGENT);
}
#define TVAL(x) __uint_as_float((unsigned)(x))
#define TTAG(x) ((unsigned)((x) >> 32))

__device__ __forceinline__ void bar_lds() {
  asm volatile("s_waitcnt lgkmcnt(0)" ::: "memory");
  __builtin_amdgcn_s_barrier();
  asm volatile("" ::: "memory");
}

__global__ __launch_bounds__(256) void setup_kernel(
    const float* __restrict__ lamb, const float* __restrict__ mu,
    const float* __restrict__ buoy, float* __restrict__ coef)
{
  __shared__ float red[256];
  const int tid = threadIdx.x;
  float m = 0.0f;
  for (int i = tid; i < 256*256; i += 256)
    m = fmaxf(m, sqrtf((lamb[i] + 2.0f*mu[i]) * buoy[i]));
  red[tid] = m;
  __syncthreads();
  for (int s = 128; s > 0; s >>= 1) {
    if (tid < s) red[tid] = fmaxf(red[tid], red[tid+s]);
    __syncthreads();
  }
  const float maxv = red[0];
  const float i_f = (float)tid;
  const float w = 20.0f;
  float f1 = fminf(fmaxf((w - i_f) * (1.0f/w), 0.0f), 1.0f);
  float f2 = fminf(fmaxf((i_f - (256.0f - 1.0f - w)) * (1.0f/w), 0.0f), 1.0f);
  float frac = fmaxf(f1, f2);
  float sigma_max = 3.0f * maxv * 6.907755278982137f / (2.0f * w * 5.0f);
  float sigma = sigma_max * frac * frac;
  float alpha = 3.14159265358979323f * 25.0f * (1.0f - frac);
  float bc = expf(-(sigma + alpha) * 0.0005f);
  float ac = sigma / (sigma + alpha + 1e-9f) * (bc - 1.0f);
  coef[tid]       = ac;  // ay
  coef[256 + tid] = bc;  // by
  coef[512 + tid] = ac;  // ax
  coef[768 + tid] = bc;  // bx
}

__global__ __launch_bounds__(256) void elastic_col(
    const float* __restrict__ lamb_g, const float* __restrict__ mu_g,
    const float* __restrict__ buoy_g, const float* __restrict__ amps,
    const int* __restrict__ src_loc, const int* __restrict__ rec_loc,
    float* __restrict__ ws, float* __restrict__ out)
{
  // tiny LDS: wave-boundary column exchange only
  __shared__ float SxyB[4][6], SxxB[4][6], VyB[4][4], VxB[4][4];

  const int blk = blockIdx.x;
  const int b = blk >> 6, bi = blk & 63;
  const int tx = threadIdx.x;          // = column
  const int lane = tx & 63, wv = tx >> 6;
  const int lo = bi << 2;
  const bool hasUp = bi > 0, hasDn = bi < 63;
  const bool xm_ok = tx > 0, xp_ok = tx < 255;

  const float* coef = ws + COEF_OFF;
  unsigned long long* exb = (unsigned long long*)(ws + EX_OFF);

  const float axv = coef[512+tx], bxv = coef[768+tx];

  // ---- per-thread column state ----
  // v rows r=0..5 <-> gy = lo-1+r ; stress rows j=0..3 <-> gy = lo+j (v-index j+1)
  float vy[6], vx[6], myy[6], myx[6], mxyy[6], mxx[6];
  float cay[6], cby[6], vdtb[6];
  #pragma unroll
  for (int r = 0; r < 6; ++r) {
    const int gy = lo - 1 + r;
    const bool ok = (gy >= 0) && (gy < 256);
    const int gc = ok ? gy : 0;
    vdtb[r] = ok ? DTv * buoy_g[gc*NXc + tx] : 0.f;
    cay[r]  = ok ? coef[gc] : 0.f;
    cby[r]  = ok ? coef[256+gc] : 1.f;
    vy[r]=vx[r]=myy[r]=myx[r]=mxyy[r]=mxx[r]=0.f;
  }
  float syy[4], sxy[4], sxx[4], mvyy[4], mvxx[4], mvyx[4], mvxy[4];
  float slam[4], smu[4], sl2m[4];
  #pragma unroll
  for (int j = 0; j < 4; ++j) {
    const int gy = lo + j;
    slam[j] = lamb_g[gy*NXc+tx]; smu[j] = mu_g[gy*NXc+tx];
    sl2m[j] = slam[j] + 2.f*smu[j];
    syy[j]=sxy[j]=sxx[j]=mvyy[j]=mvxx[j]=mvyx[j]=mvxy[j]=0.f;
  }

  // ---- sources (v-rows incl. halo replicas; inject consistently) ----
  int sk0=-1, sk1=-1, so0=0, so1=0;
  for (int i = 0; i < 4; ++i) {
    const int sb = i >> 1, sy = src_loc[2*i], sx = src_loc[2*i+1];
    if (sb == b && sx == tx) {
      const int r = sy - (lo - 1);
      if (r >= 0 && r < 6) { if (sk0 < 0) { sk0=r; so0=i*NTc; } else { sk1=r; so1=i*NTc; } }
    }
  }
  // ---- receivers: own rows (j=0..3), bitmasks; static-j passes (reg-safe) ----
  unsigned long long rL0=0,rH0=0,rL1=0,rH1=0,rL2=0,rH2=0,rL3=0,rH3=0;
  for (int i = 0; i < 128; ++i) {
    const int rb = i >> 6, ry = rec_loc[2*i], rx = rec_loc[2*i+1];
    if (rb == b && rx == tx) {
      const unsigned long long bit = 1ull << (i & 63);
      if (ry == lo)   { if (i<64) rL0|=bit; else rH0|=bit; }
      if (ry == lo+1) { if (i<64) rL1|=bit; else rH1|=bit; }
      if (ry == lo+2) { if (i<64) rL2|=bit; else rH2|=bit; }
      if (ry == lo+3) { if (i<64) rL3|=bit; else rH3|=bit; }
    }
  }
  const bool anyrec = (rL0|rH0|rL1|rH1|rL2|rH2|rL3|rH3) != 0ull;

  // zero boundary LDS
  if (tx < 4*6) { SxyB[tx/6][tx%6]=0.f; SxxB[tx/6][tx%6]=0.f; }
  if (tx < 4*4) { VyB[tx/4][tx%4]=0.f;  VxB[tx/4][tx%4]=0.f; }
  __syncthreads();

  for (int t = 0; t < NTc; ++t) {
    float a0=0.f, a1=0.f;
    if (sk0>=0) a0 = amps[so0+t];
    if (sk1>=0) a1 = amps[so1+t];

    // ========== tagged ingest: poll until all 8 words carry tag t ==========
    unsigned long long uw0=0,uw1=0,uw2=0,uw3=0, dw0=0,dw1=0,dw2=0,dw3=0;
    if (t > 0) {
      const size_t ps = (size_t)((t-1)&1)*NBLK;
      const unsigned long long* up = exb + (ps + (hasUp?blk-1:blk))*EX_BLK + tx;
      const unsigned long long* dn = exb + (ps + (hasDn?blk+1:blk))*EX_BLK + tx;
      const unsigned want = (unsigned)t;
      for (;;) {
        if (hasUp) { uw0=tld(up+4*256); uw1=tld(up+5*256); uw2=tld(up+6*256); uw3=tld(up+7*256); }
        if (hasDn) { dw0=tld(dn+0*256); dw1=tld(dn+1*256); dw2=tld(dn+2*256); dw3=tld(dn+3*256); }
        bool ok = true;
        if (hasUp) ok = ok && TTAG(uw0)==want && TTAG(uw1)==want && TTAG(uw2)==want && TTAG(uw3)==want;
        if (hasDn) ok = ok && TTAG(dw0)==want && TTAG(dw1)==want && TTAG(dw2)==want && TTAG(dw3)==want;
        if (ok) break;
      }
    }
    const float syyU2=TVAL(uw0), syyU1=TVAL(uw1), sxyU1=TVAL(uw2), sxxU1=TVAL(uw3);
    const float syyD =TVAL(dw0), sxyD4=TVAL(dw1), sxyD5=TVAL(dw2), sxxD =TVAL(dw3);

    // halo boundary-lane LDS (for cross-wave x-neighbors of ingested rows)
    if (lane == 63) { SxyB[wv][0]=sxyU1; SxyB[wv][5]=sxyD4; }
    if (lane == 0)  { SxxB[wv][0]=sxxU1; SxxB[wv][5]=sxxD; }
    bar_lds();   // covers halo writes + prev step's own-row boundary writes

    // ========== A: velocity on rows r=0..5 (y in registers, x by shuffle) ==========
    {
      const float syE[7]  = {syyU2, syyU1, syy[0],syy[1],syy[2],syy[3], syyD};
      const float sxyE[6] = {sxyU1, sxy[0],sxy[1],sxy[2],sxy[3], sxyD4};
      const float sxxE[6] = {sxxU1, sxx[0],sxx[1],sxx[2],sxx[3], sxxD};
      #pragma unroll
      for (int r = 0; r < 6; ++r) {
        float sxym = __shfl_up(sxyE[r], 1, 64);
        if (lane == 0 && wv > 0) sxym = SxyB[wv-1][r];
        float sxxp = __shfl_down(sxxE[r], 1, 64);
        if (lane == 63 && wv < 3) sxxp = SxxB[wv+1][r];
        if (r == 0 && !hasUp) continue;
        if (r == 5 && !hasDn) continue;
        const int gy = lo - 1 + r;
        float d, u1, u2, u3, u4;
        d = (gy > 0) ? (syE[r+1] - syE[r]) * INVD : 0.f;          // dby syy
        myy[r] = cby[r]*myy[r] + cay[r]*d; u1 = d + myy[r];
        d = xm_ok ? (sxyE[r] - sxym) * INVD : 0.f;                // dbx sxy
        myx[r] = bxv*myx[r] + axv*d; u2 = d + myx[r];
        vy[r] += vdtb[r]*(u1+u2);
        float dfy;
        if (r < 5) dfy = (gy < 255) ? (sxyE[r+1] - sxyE[r]) * INVD : 0.f;
        else       dfy = (sxyD5 - sxyD4) * INVD;                  // gy=lo+4<=252
        mxyy[r] = cby[r]*mxyy[r] + cay[r]*dfy; u3 = dfy + mxyy[r];
        d = xp_ok ? (sxxp - sxxE[r]) * INVD : 0.f;                // dfx sxx
        mxx[r] = bxv*mxx[r] + axv*d; u4 = d + mxx[r];
        vx[r] += vdtb[r]*(u3+u4);
        if (r == sk0) vy[r] += a0*vdtb[r];
        if (r == sk1) vy[r] += a1*vdtb[r];
      }
    }
    // v boundary-lane exchange for B's dbx
    if (lane == 63) {
      VyB[wv][0]=vy[1]; VyB[wv][1]=vy[2]; VyB[wv][2]=vy[3]; VyB[wv][3]=vy[4];
      VxB[wv][0]=vx[1]; VxB[wv][1]=vx[2]; VxB[wv][2]=vx[3]; VxB[wv][3]=vx[4];
    }
    bar_lds();

    // recording (post-inject, off the sync path)
    if (anyrec) {
      unsigned long long m;
      m=rL0; while(m){int i=__ffsll((long long)m)-1;m&=m-1;out[i*NTc+t]=vy[1];}
      m=rH0; while(m){int i=__ffsll((long long)m)-1;m&=m-1;out[(i+64)*NTc+t]=vy[1];}
      m=rL1; while(m){int i=__ffsll((long long)m)-1;m&=m-1;out[i*NTc+t]=vy[2];}
      m=rH1; while(m){int i=__ffsll((long long)m)-1;m&=m-1;out[(i+64)*NTc+t]=vy[2];}
      m=rL2; while(m){int i=__ffsll((long long)m)-1;m&=m-1;out[i*NTc+t]=vy[3];}
      m=rH2; while(m){int i=__ffsll((long long)m)-1;m&=m-1;out[(i+64)*NTc+t]=vy[3];}
      m=rL3; while(m){int i=__ffsll((long long)m)-1;m&=m-1;out[i*NTc+t]=vy[4];}
      m=rH3; while(m){int i=__ffsll((long long)m)-1;m&=m-1;out[(i+64)*NTc+t]=vy[4];}
    }

    // ========== B: stress on own rows j=0..3 ==========
    {
      float vym[4], vxm[4];
      #pragma unroll
      for (int j = 0; j < 4; ++j) {
        vym[j] = __shfl_up(vy[j+1], 1, 64);
        vxm[j] = __shfl_up(vx[j+1], 1, 64);
        if (lane == 0 && wv > 0) { vym[j] = VyB[wv-1][j]; vxm[j] = VxB[wv-1][j]; }
      }
      #pragma unroll
      for (int j = 0; j < 4; ++j) {
        const int gy = lo + j;
        float d, u5, u6, u7, u8;
        d = (gy < 255) ? (vy[j+2] - vy[j+1]) * INVD : 0.f;        // dfy vy
        mvyy[j] = cby[j+1]*mvyy[j] + cay[j+1]*d; u5 = d + mvyy[j];
        d = xm_ok ? (vx[j+1] - vxm[j]) * INVD : 0.f;              // dbx vx
        mvxx[j] = bxv*mvxx[j] + axv*d; u6 = d + mvxx[j];
        syy[j] += DTv*(sl2m[j]*u5 + slam[j]*u6);
        sxx[j] += DTv*(slam[j]*u5 + sl2m[j]*u6);
        d = xm_ok ? (vy[j+1] - vym[j]) * INVD : 0.f;              // dbx vy
        mvyx[j] = bxv*mvyx[j] + axv*d; u7 = d + mvyx[j];
        d = (gy > 0) ? (vx[j+1] - vx[j]) * INVD : 0.f;            // dby vx
        mvxy[j] = cby[j+1]*mvxy[j] + cay[j+1]*d; u8 = d + mvxy[j];
        sxy[j] += DTv*smu[j]*(u7+u8);
      }
    }

    // egress: 8 tagged words (self-validating; no drain, no flag)
    {
      unsigned long long* Q = exb + ((size_t)(t&1)*NBLK + blk)*EX_BLK + tx;
      const unsigned wt = (unsigned)(t+1);
      tst(Q+0*256, syy[0], wt); tst(Q+1*256, sxy[0], wt);
      tst(Q+2*256, sxy[1], wt); tst(Q+3*256, sxx[0], wt);
      tst(Q+4*256, syy[2], wt); tst(Q+5*256, syy[3], wt);
      tst(Q+6*256, sxy[3], wt); tst(Q+7*256, sxx[3], wt);
    }
    // own-row boundary stress for next step's A (covered by next barrier A)
    if (lane == 63) { SxyB[wv][1]=sxy[0]; SxyB[wv][2]=sxy[1]; SxyB[wv][3]=sxy[2]; SxyB[wv][4]=sxy[3]; }
    if (lane == 0)  { SxxB[wv][1]=sxx[0]; SxxB[wv][2]=sxx[1]; SxxB[wv][3]=sxx[2]; SxxB[wv][4]=sxx[3]; }
  }
}

extern "C" void kernel_launch(void* const* d_in, const int* in_sizes, int n_in,
                              void* d_out, int out_size, void* d_ws, size_t ws_size,
                              hipStream_t stream) {
  const float* lamb    = (const float*)d_in[0];
  const float* mu      = (const float*)d_in[1];
  const float* buoy    = (const float*)d_in[2];
  const float* amps    = (const float*)d_in[3];
  const int*   src_loc = (const int*)d_in[4];
  const int*   rec_loc = (const int*)d_in[5];
  float* out = (float*)d_out;
  float* ws  = (float*)d_ws;

  // tag region must start at 0 every launch (tags 1..256 within one run)
  hipMemsetAsync((char*)ws + EX_OFF*sizeof(float), 0,
                 (size_t)2*NBLK*EX_BLK*sizeof(unsigned long long), stream);

  hipLaunchKernelGGL(setup_kernel, dim3(1), dim3(256), 0, stream,
                     lamb, mu, buoy, ws + COEF_OFF);

  void* args[] = { (void*)&lamb, (void*)&mu, (void*)&buoy, (void*)&amps,
                   (void*)&src_loc, (void*)&rec_loc, (void*)&ws, (void*)&out };
  hipLaunchCooperativeKernel((void*)elastic_col, dim3(NBLK), dim3(256),
                             args, 0, stream);
}